// Round 8
// baseline (161.035 us; speedup 1.0000x reference)
//
#include <hip/hip_runtime.h>
#include <stdint.h>

#define NPTS 4096
#define NC 128
#define NB 8
#define CSPLIT 4
#define COLS_PER (NPTS / CSPLIT)  // 1024
#define RPB 128                   // rows per block (4 waves x 32 rows)

typedef __bf16 bf16x8 __attribute__((ext_vector_type(8)));
typedef float f32x4 __attribute__((ext_vector_type(4)));
typedef unsigned short u16;
typedef unsigned int u32;

// raw v_exp_f32 (exp2); NOTE plain __exp2f collides with glibc math.h macros
__device__ inline float fast_exp2(float x) { return __builtin_amdgcn_exp2f(x); }

__device__ inline u16 f2bf(float x) {
    u32 u = __float_as_uint(x);
    u32 r = (u + 0x7fffu + ((u >> 16) & 1u)) >> 16;
    return (u16)r;
}

// Kernel 1: normalize (blocks 0..63) + histogram & ws zeroing (block 64).
__global__ __launch_bounds__(256) void norm_count_kernel(const float* __restrict__ feat,
                                                         const int* __restrict__ labels,
                                                         u16* __restrict__ vbf,
                                                         int* __restrict__ counts,
                                                         u32* __restrict__ zbase) {
    int b = blockIdx.y;
    int tid = threadIdx.x;
    if (blockIdx.x == 64) {  // histogram branch (+ zero acc/ticket, 1 cloud only)
        if (b == 0 && tid < 2) zbase[tid] = 0u;
        __shared__ int h[16];
        if (tid < 16) h[tid] = 0;
        __syncthreads();
        for (int n = tid; n < NPTS; n += 256)
            atomicAdd(&h[labels[b * NPTS + n] & 15], 1);
        __syncthreads();
        if (tid < 16) counts[b * 16 + tid] = h[tid];
        return;
    }
    int n0 = blockIdx.x * 64;
    __shared__ float tile[64][129];
    __shared__ float part[8][64];
    __shared__ float rn[64];
    const float* fb = feat + (size_t)b * NC * NPTS;
    int nslot = tid & 31;  // point pair 2*nslot, 2*nslot+1
    int ty = tid >> 5;     // 0..7 c-group
    float s0 = 0.f, s1 = 0.f;
#pragma unroll
    for (int i = 0; i < 16; ++i) {
        int c = i * 8 + ty;
        float2 x = *(const float2*)(fb + (size_t)c * NPTS + n0 + 2 * nslot);
        tile[2 * nslot][c] = x.x;
        tile[2 * nslot + 1][c] = x.y;
        s0 += x.x * x.x;
        s1 += x.y * x.y;
    }
    part[ty][2 * nslot] = s0;
    part[ty][2 * nslot + 1] = s1;
    __syncthreads();
    if (tid < 64) {
        float s = 0.f;
#pragma unroll
        for (int t = 0; t < 8; ++t) s += part[t][tid];
        rn[tid] = 1.f / fmaxf(sqrtf(s), 1e-12f);
    }
    __syncthreads();
    u32* out = (u32*)vbf;
    size_t obase = ((size_t)b * NPTS + n0) * (NC / 2);
#pragma unroll
    for (int i = 0; i < 16; ++i) {
        int idx = tid + i * 256;
        int p = idx >> 6, k = idx & 63;
        float r = rn[p];
        float x0 = tile[p][2 * k] * r;
        float x1 = tile[p][2 * k + 1] * r;
        out[obase + (size_t)p * 64 + k] = (u32)f2bf(x0) | ((u32)f2bf(x1) << 16);
    }
}

// Kernel 2: similarity + exp2 + masked row partial sums.
// Grid 1024 = 8 clouds x 32 rowtiles x 4 colsplits = 4 blocks/CU in one pass.
// 128 rows x 1024 cols/block; 32 rows/wave. XOR-swizzled LDS (0 conflicts).
//
// REGISTER BUDGET (hard-won): gfx950 caps ARCH VGPRs at 256/min_waves:
//   (256,8)->32, (256,5)->48 [R3 spill], (256,4)->64 [R5 spill], (256,2)->128.
//   Hot loop ~100 VGPRs incl. prefetch -> keep (256,2). Tripwire: WRITE_SIZE
//   ballooning to 100s of MB = scratch spill.
//
// R8: double-buffered LDS (ONE barrier/tile: write buf[t&1] -> prefetch t+1
// -> barrier -> compute; prior tile's compute overlaps next tile's loads) +
// A-frags pre-scaled by log2(e) so epilogue exp is a bare v_exp_f32.
__global__ __launch_bounds__(256, 2) void sim_kernel(const u16* __restrict__ vbf,
                                                     const int* __restrict__ labels,
                                                     float2* __restrict__ rowacc) {
    int bid = blockIdx.x;
    int rt = bid >> 5;
    int combo = bid & 31;  // (cloud, cs): round-robin XCD dispatch gives each
    int b = combo >> 2;    // XCD 4 distinct 1 MB col-slabs = its 4 MB L2
    int cs = combo & 3;
    int row0 = rt * RPB;
    int c0 = cs * COLS_PER;
    int tid = threadIdx.x;
    int wave = tid >> 6, lane = tid & 63;
    int quad = lane >> 4, ln = lane & 15;

    const u16* vb = vbf + (size_t)b * NPTS * NC;
    const int* lab = labels + b * NPTS;

    int rbase[2];
    rbase[0] = row0 + wave * 32;
    rbase[1] = rbase[0] + 16;

    // A fragments, pre-scaled by log2(e): exp(dot) == exp2(scaled_dot)
    bf16x8 afrag[2][4];
#pragma unroll
    for (int s = 0; s < 2; ++s)
#pragma unroll
        for (int f = 0; f < 4; ++f) {
            bf16x8 v = *(const bf16x8*)(vb + (size_t)(rbase[s] + ln) * NC + f * 32 + quad * 8);
#pragma unroll
            for (int k = 0; k < 8; ++k) v[k] = (__bf16)((float)v[k] * 1.44269504f);
            afrag[s][f] = v;
        }

    int lrow[2][4];
#pragma unroll
    for (int s = 0; s < 2; ++s)
#pragma unroll
        for (int r = 0; r < 4; ++r) lrow[s][r] = lab[rbase[s] + quad * 4 + r];

    int diagct[2], diagsub[2];
#pragma unroll
    for (int s = 0; s < 2; ++s) {
        diagct[s] = rbase[s] & ~63;
        diagsub[s] = (rbase[s] >> 4) & 3;
    }

    float psame[2][4] = {{0.f}}, sall[2][4] = {{0.f}};

    __shared__ u16 cols[2][64 * 128];
    __shared__ int clab[2][64];

    const uint4* src = (const uint4*)(vb + (size_t)c0 * NC);
    u32 woff[4];
#pragma unroll
    for (int i = 0; i < 4; ++i) {
        int idx = tid + i * 256;
        int rr = idx >> 4, cc = idx & 15;
        woff[i] = rr * 128 + ((cc ^ (rr & 15)) * 8);
    }

    uint4 pf[4];
#pragma unroll
    for (int i = 0; i < 4; ++i) pf[i] = src[tid + i * 256];
    int plab = (tid < 64) ? lab[c0 + tid] : 0;

    for (int t = 0; t < COLS_PER / 64; ++t) {
        int ct = c0 + t * 64;
        int cur = t & 1;
        u16* bufc = cols[cur];
#pragma unroll
        for (int i = 0; i < 4; ++i) *(uint4*)(bufc + woff[i]) = pf[i];
        if (tid < 64) clab[cur][tid] = plab;
        if (t + 1 < COLS_PER / 64) {
#pragma unroll
            for (int i = 0; i < 4; ++i) pf[i] = src[(t + 1) * 1024 + tid + i * 256];
            if (tid < 64) plab = lab[ct + 64 + tid];
        }
        __syncthreads();  // buf[cur] ready; prev tile's reads were from buf[1-cur]

#pragma unroll
        for (int sub = 0; sub < 4; ++sub) {
            const u16* rowb = bufc + (sub * 16 + ln) * 128;
            bf16x8 bfrag[4];
#pragma unroll
            for (int f = 0; f < 4; ++f)
                bfrag[f] = *(const bf16x8*)(rowb + (((4 * f + quad) ^ ln) * 8));
            int lc = clab[cur][sub * 16 + ln];
#pragma unroll
            for (int s = 0; s < 2; ++s) {
                f32x4 d = {0.f, 0.f, 0.f, 0.f};
#pragma unroll
                for (int f = 0; f < 4; ++f)
                    d = __builtin_amdgcn_mfma_f32_16x16x32_bf16(afrag[s][f], bfrag[f], d, 0, 0, 0);
                if (ct == diagct[s] && sub == diagsub[s]) {  // wave-uniform, rare
#pragma unroll
                    for (int r = 0; r < 4; ++r) {
                        float e = fast_exp2(d[r]);
                        if (ln == quad * 4 + r) e = 0.f;  // zero the diagonal
                        sall[s][r] += e;
                        psame[s][r] += (lc == lrow[s][r]) ? e : 0.f;
                    }
                } else {
#pragma unroll
                    for (int r = 0; r < 4; ++r) {
                        float e = fast_exp2(d[r]);
                        sall[s][r] += e;
                        psame[s][r] += (lc == lrow[s][r]) ? e : 0.f;
                    }
                }
            }
        }
    }

#pragma unroll
    for (int off = 1; off < 16; off <<= 1)
#pragma unroll
        for (int s = 0; s < 2; ++s)
#pragma unroll
            for (int r = 0; r < 4; ++r) {
                psame[s][r] += __shfl_xor(psame[s][r], off);
                sall[s][r] += __shfl_xor(sall[s][r], off);
            }
    if (ln == 0) {
#pragma unroll
        for (int s = 0; s < 2; ++s)
#pragma unroll
            for (int r = 0; r < 4; ++r)
                rowacc[((size_t)cs * NB + b) * NPTS + rbase[s] + quad * 4 + r] =
                    make_float2(psame[s][r], sall[s][r]);
    }
}

// Kernel 3: per-row finalize + mean; last block (ticket) writes d_out.
__global__ __launch_bounds__(256) void loss_kernel(const float2* __restrict__ rowacc,
                                                   const int* __restrict__ labels,
                                                   const int* __restrict__ counts,
                                                   float* __restrict__ acc,
                                                   u32* __restrict__ ticket,
                                                   float* __restrict__ out) {
    int idx = blockIdx.x * 256 + threadIdx.x;  // 0..B*NPTS-1
    int b = idx >> 12;
    float ps = 0.f, sa = 0.f;
#pragma unroll
    for (int cs = 0; cs < CSPLIT; ++cs) {
        float2 v = rowacc[(size_t)cs * NB * NPTS + idx];
        ps += v.x;
        sa += v.y;
    }
    int lb = labels[idx] & 15;
    int cnt = counts[b * 16 + lb];
    float p = ps / (float)cnt;
    float n = (sa - ps) / (float)(NPTS - cnt);
    float loss = -__logf(p / (p + n));
#pragma unroll
    for (int off = 1; off < 64; off <<= 1) loss += __shfl_xor(loss, off);
    __shared__ float w[4];
    if ((threadIdx.x & 63) == 0) w[threadIdx.x >> 6] = loss;
    __syncthreads();
    if (threadIdx.x == 0) {
        atomicAdd(acc, w[0] + w[1] + w[2] + w[3]);
        __threadfence();
        u32 t = atomicAdd(ticket, 1u);
        if (t == gridDim.x - 1) {  // all blocks' adds visible (fence + ticket)
            float v = atomicAdd(acc, 0.f);  // coherent read of final sum
            out[0] = v * (1.f / (float)(NB * NPTS));
        }
    }
}

extern "C" void kernel_launch(void* const* d_in, const int* in_sizes, int n_in,
                              void* d_out, int out_size, void* d_ws, size_t ws_size,
                              hipStream_t stream) {
    const float* feat = (const float*)d_in[0];
    const int* labels = (const int*)d_in[1];
    float* out = (float*)d_out;

    float* acc = (float*)d_ws;                       // @0, 4 B
    u32* ticket = (u32*)((char*)d_ws + 4);           // @4, 4 B
    int* counts = (int*)((char*)d_ws + 256);         // @256, 64 B
    float2* rowacc = (float2*)((char*)d_ws + 4096);  // 4*8*4096*8 = 1 MB
    u16* vbf = (u16*)((char*)d_ws + 4096 + (size_t)CSPLIT * NB * NPTS * 8);  // 8 MB

    norm_count_kernel<<<dim3(65, NB), 256, 0, stream>>>(feat, labels, vbf, counts, (u32*)d_ws);
    sim_kernel<<<dim3(32 * 32), 256, 0, stream>>>(vbf, labels, rowacc);
    loss_kernel<<<dim3(NB * NPTS / 256), 256, 0, stream>>>(rowacc, labels, counts, acc, ticket, out);
}

// Round 9
// 131.974 us; speedup vs baseline: 1.2202x; 1.2202x over previous
//
#include <hip/hip_runtime.h>
#include <stdint.h>

#define NPTS 4096
#define NC 128
#define NB 8
#define CSPLIT 8
#define COLS_PER (NPTS / CSPLIT)  // 512
#define RPB 128                   // rows per block (4 waves x 32 rows)

typedef __bf16 bf16x8 __attribute__((ext_vector_type(8)));
typedef float f32x4 __attribute__((ext_vector_type(4)));
typedef unsigned short u16;
typedef unsigned int u32;

// raw v_exp_f32 (exp2); NOTE plain __exp2f collides with glibc math.h macros
__device__ inline float fast_exp2(float x) { return __builtin_amdgcn_exp2f(x); }

__device__ inline u16 f2bf(float x) {
    u32 u = __float_as_uint(x);
    u32 r = (u + 0x7fffu + ((u >> 16) & 1u)) >> 16;
    return (u16)r;
}

// Kernel 1: normalize (blocks 0..63) + histogram & ws zeroing (block 64).
__global__ __launch_bounds__(256) void norm_count_kernel(const float* __restrict__ feat,
                                                         const int* __restrict__ labels,
                                                         u16* __restrict__ vbf,
                                                         int* __restrict__ counts,
                                                         u32* __restrict__ zbase) {
    int b = blockIdx.y;
    int tid = threadIdx.x;
    if (blockIdx.x == 64) {  // histogram branch (+ zero acc/ticket, 1 cloud only)
        if (b == 0 && tid < 2) zbase[tid] = 0u;
        __shared__ int h[16];
        if (tid < 16) h[tid] = 0;
        __syncthreads();
        for (int n = tid; n < NPTS; n += 256)
            atomicAdd(&h[labels[b * NPTS + n] & 15], 1);
        __syncthreads();
        if (tid < 16) counts[b * 16 + tid] = h[tid];
        return;
    }
    int n0 = blockIdx.x * 64;
    __shared__ float tile[64][129];
    __shared__ float part[8][64];
    __shared__ float rn[64];
    const float* fb = feat + (size_t)b * NC * NPTS;
    int nslot = tid & 31;  // point pair 2*nslot, 2*nslot+1
    int ty = tid >> 5;     // 0..7 c-group
    float s0 = 0.f, s1 = 0.f;
#pragma unroll
    for (int i = 0; i < 16; ++i) {
        int c = i * 8 + ty;
        float2 x = *(const float2*)(fb + (size_t)c * NPTS + n0 + 2 * nslot);
        tile[2 * nslot][c] = x.x;
        tile[2 * nslot + 1][c] = x.y;
        s0 += x.x * x.x;
        s1 += x.y * x.y;
    }
    part[ty][2 * nslot] = s0;
    part[ty][2 * nslot + 1] = s1;
    __syncthreads();
    if (tid < 64) {
        float s = 0.f;
#pragma unroll
        for (int t = 0; t < 8; ++t) s += part[t][tid];
        rn[tid] = 1.f / fmaxf(sqrtf(s), 1e-12f);
    }
    __syncthreads();
    u32* out = (u32*)vbf;
    size_t obase = ((size_t)b * NPTS + n0) * (NC / 2);
#pragma unroll
    for (int i = 0; i < 16; ++i) {
        int idx = tid + i * 256;
        int p = idx >> 6, k = idx & 63;
        float r = rn[p];
        float x0 = tile[p][2 * k] * r;
        float x1 = tile[p][2 * k + 1] * r;
        out[obase + (size_t)p * 64 + k] = (u32)f2bf(x0) | ((u32)f2bf(x1) << 16);
    }
}

// Kernel 2: similarity + exp2 + masked row partial sums.
// R9 = R6's proven loop (two barriers/tile, NO reg-prefetch, NO LDS dbuf:
// both caused scratch spills -- R8 WRITE_SIZE 49 MB; R6 = 1 MB) with:
//   * CSPLIT=8 -> grid 2048. At 76 VGPR the HW fits 6 blocks/CU (512/76
//     waves/SIMD); CSPLIT=4's 1024-block grid left capacity idle at 4/CU.
//   * A-frags pre-scaled by log2(e) -> epilogue exp is bare v_exp_f32.
//
// REGISTER BUDGET (hard-won): gfx950 caps ARCH VGPRs at 256/min_waves:
//   (256,8)->32, (256,5)->48 [R3 spill], (256,4)->64 [R5 spill], (256,2)->128.
//   Tripwire: WRITE_SIZE in the 10s-100s of MB = scratch spill.
__global__ __launch_bounds__(256, 2) void sim_kernel(const u16* __restrict__ vbf,
                                                     const int* __restrict__ labels,
                                                     float2* __restrict__ rowacc) {
    int bid = blockIdx.x;
    int rt = bid >> 6;
    int combo = bid & 63;  // (cloud, cs): round-robin XCD dispatch spreads
    int b = combo >> 3;    // col-slabs across XCD L2s
    int cs = combo & 7;
    int row0 = rt * RPB;
    int c0 = cs * COLS_PER;
    int tid = threadIdx.x;
    int wave = tid >> 6, lane = tid & 63;
    int quad = lane >> 4, ln = lane & 15;

    const u16* vb = vbf + (size_t)b * NPTS * NC;
    const int* lab = labels + b * NPTS;

    int rbase[2];
    rbase[0] = row0 + wave * 32;
    rbase[1] = rbase[0] + 16;

    // A fragments, pre-scaled by log2(e): exp(dot) == exp2(scaled_dot)
    bf16x8 afrag[2][4];
#pragma unroll
    for (int s = 0; s < 2; ++s)
#pragma unroll
        for (int f = 0; f < 4; ++f) {
            bf16x8 v = *(const bf16x8*)(vb + (size_t)(rbase[s] + ln) * NC + f * 32 + quad * 8);
#pragma unroll
            for (int k = 0; k < 8; ++k) v[k] = (__bf16)((float)v[k] * 1.44269504f);
            afrag[s][f] = v;
        }

    int lrow[2][4];
#pragma unroll
    for (int s = 0; s < 2; ++s)
#pragma unroll
        for (int r = 0; r < 4; ++r) lrow[s][r] = lab[rbase[s] + quad * 4 + r];

    int diagct[2], diagsub[2];
#pragma unroll
    for (int s = 0; s < 2; ++s) {
        diagct[s] = rbase[s] & ~63;   // fires only in the cs covering these cols
        diagsub[s] = (rbase[s] >> 4) & 3;
    }

    float psame[2][4] = {{0.f}}, sall[2][4] = {{0.f}};

    __shared__ u16 cols[64 * 128];
    __shared__ int clab[64];

    const uint4* src = (const uint4*)(vb + (size_t)c0 * NC);
    u32 woff[4];
#pragma unroll
    for (int i = 0; i < 4; ++i) {
        int idx = tid + i * 256;
        int rr = idx >> 4, cc = idx & 15;
        woff[i] = rr * 128 + ((cc ^ (rr & 15)) * 8);  // XOR swizzle: 0 conflicts
    }

    for (int t = 0; t < COLS_PER / 64; ++t) {
        int ct = c0 + t * 64;
        __syncthreads();
#pragma unroll
        for (int i = 0; i < 4; ++i)
            *(uint4*)(cols + woff[i]) = src[t * 1024 + tid + i * 256];
        if (tid < 64) clab[tid] = lab[ct + tid];
        __syncthreads();

#pragma unroll
        for (int sub = 0; sub < 4; ++sub) {
            const u16* rowb = cols + (sub * 16 + ln) * 128;
            bf16x8 bfrag[4];
#pragma unroll
            for (int f = 0; f < 4; ++f)
                bfrag[f] = *(const bf16x8*)(rowb + (((4 * f + quad) ^ ln) * 8));
            int lc = clab[sub * 16 + ln];
#pragma unroll
            for (int s = 0; s < 2; ++s) {
                f32x4 d = {0.f, 0.f, 0.f, 0.f};
#pragma unroll
                for (int f = 0; f < 4; ++f)
                    d = __builtin_amdgcn_mfma_f32_16x16x32_bf16(afrag[s][f], bfrag[f], d, 0, 0, 0);
                if (ct == diagct[s] && sub == diagsub[s]) {  // wave-uniform, rare
#pragma unroll
                    for (int r = 0; r < 4; ++r) {
                        float e = fast_exp2(d[r]);
                        if (ln == quad * 4 + r) e = 0.f;  // zero the diagonal
                        sall[s][r] += e;
                        psame[s][r] += (lc == lrow[s][r]) ? e : 0.f;
                    }
                } else {
#pragma unroll
                    for (int r = 0; r < 4; ++r) {
                        float e = fast_exp2(d[r]);
                        sall[s][r] += e;
                        psame[s][r] += (lc == lrow[s][r]) ? e : 0.f;
                    }
                }
            }
        }
    }

#pragma unroll
    for (int off = 1; off < 16; off <<= 1)
#pragma unroll
        for (int s = 0; s < 2; ++s)
#pragma unroll
            for (int r = 0; r < 4; ++r) {
                psame[s][r] += __shfl_xor(psame[s][r], off);
                sall[s][r] += __shfl_xor(sall[s][r], off);
            }
    if (ln == 0) {
#pragma unroll
        for (int s = 0; s < 2; ++s)
#pragma unroll
            for (int r = 0; r < 4; ++r)
                rowacc[((size_t)cs * NB + b) * NPTS + rbase[s] + quad * 4 + r] =
                    make_float2(psame[s][r], sall[s][r]);
    }
}

// Kernel 3: per-row finalize + mean; last block (ticket) writes d_out.
__global__ __launch_bounds__(256) void loss_kernel(const float2* __restrict__ rowacc,
                                                   const int* __restrict__ labels,
                                                   const int* __restrict__ counts,
                                                   float* __restrict__ acc,
                                                   u32* __restrict__ ticket,
                                                   float* __restrict__ out) {
    int idx = blockIdx.x * 256 + threadIdx.x;  // 0..B*NPTS-1
    int b = idx >> 12;
    float ps = 0.f, sa = 0.f;
#pragma unroll
    for (int cs = 0; cs < CSPLIT; ++cs) {
        float2 v = rowacc[(size_t)cs * NB * NPTS + idx];
        ps += v.x;
        sa += v.y;
    }
    int lb = labels[idx] & 15;
    int cnt = counts[b * 16 + lb];
    float p = ps / (float)cnt;
    float n = (sa - ps) / (float)(NPTS - cnt);
    float loss = -__logf(p / (p + n));
#pragma unroll
    for (int off = 1; off < 64; off <<= 1) loss += __shfl_xor(loss, off);
    __shared__ float w[4];
    if ((threadIdx.x & 63) == 0) w[threadIdx.x >> 6] = loss;
    __syncthreads();
    if (threadIdx.x == 0) {
        atomicAdd(acc, w[0] + w[1] + w[2] + w[3]);
        __threadfence();
        u32 t = atomicAdd(ticket, 1u);
        if (t == gridDim.x - 1) {  // all blocks' adds visible (fence + ticket)
            float v = atomicAdd(acc, 0.f);  // coherent read of final sum
            out[0] = v * (1.f / (float)(NB * NPTS));
        }
    }
}

extern "C" void kernel_launch(void* const* d_in, const int* in_sizes, int n_in,
                              void* d_out, int out_size, void* d_ws, size_t ws_size,
                              hipStream_t stream) {
    const float* feat = (const float*)d_in[0];
    const int* labels = (const int*)d_in[1];
    float* out = (float*)d_out;

    float* acc = (float*)d_ws;                       // @0, 4 B
    u32* ticket = (u32*)((char*)d_ws + 4);           // @4, 4 B
    int* counts = (int*)((char*)d_ws + 256);         // @256, 64 B
    float2* rowacc = (float2*)((char*)d_ws + 4096);  // 8*8*4096*8 = 2 MB
    u16* vbf = (u16*)((char*)d_ws + 4096 + (size_t)CSPLIT * NB * NPTS * 8);  // 8 MB

    norm_count_kernel<<<dim3(65, NB), 256, 0, stream>>>(feat, labels, vbf, counts, (u32*)d_ws);
    sim_kernel<<<dim3(32 * 64), 256, 0, stream>>>(vbf, labels, rowacc);
    loss_kernel<<<dim3(NB * NPTS / 256), 256, 0, stream>>>(rowacc, labels, counts, acc, ticket, out);
}